// Round 11
// baseline (576.632 us; speedup 1.0000x reference)
//
#include <hip/hip_runtime.h>
#include <stdint.h>

#define BB 64
#define TT 128
#define INF 257
#define KP 288
#define HH 1024
#define G4 4096
#define GLS 20            // gl row stride (floats)
#define GLI (32 * GLS + 64)  // padded inner extent -> 88KB LDS, forces 1 block/CU

// swizzled y layout: [t][ug(64)][mgp(2)][r(32)][c(16)] fp16
//   element (t, row, col): ug=col>>4, c=col&15, mgp=row>>5, r=row&31
//   offset = t*65536 + ug*1024 + mgp*512 + r*16 + c
// swizzled xg0 layout: [t][ug(64)][mgp(2)][g(4)][r(32)][c(16)] fp16
//   element (t, b, n=g*1024+col): offset = t*262144 + ug*4096 + mgp*2048
//                                          + g*512 + r*16 + c
// => every rec-block's per-step I/O is block-contiguous; a wave's per-gate
//    xg read is 64 consecutive fp16 = ONE 128B line (was 4+ lines).

typedef _Float16 half8 __attribute__((ext_vector_type(8)));
typedef float f4 __attribute__((ext_vector_type(4)));
typedef unsigned u32x4 __attribute__((ext_vector_type(4)));

__device__ __forceinline__ f4 mfma16(half8 a, half8 b, f4 c) {
  return __builtin_amdgcn_mfma_f32_16x16x32_f16(a, b, c, 0, 0, 0);
}

// LDS-only barrier: orders ds ops but does NOT drain vmcnt (h-stores stay async)
__device__ __forceinline__ void barrier_lds() {
  asm volatile("s_waitcnt lgkmcnt(0)\n\ts_barrier" ::: "memory");
}

// fast tanh via v_exp: tanh(x) = 1 - 2/(1+e^{2x}); saturates to +-1, no NaN path
__device__ __forceinline__ float ftanh(float x) {
  return 1.f - 2.f / (1.f + __expf(2.f * x));
}

// async global->LDS, 16B per lane
__device__ __forceinline__ void gld_lds16(const void* g, void* l) {
  auto gp = reinterpret_cast<__attribute__((address_space(1))) void*>(reinterpret_cast<uintptr_t>(g));
  auto lp = reinterpret_cast<__attribute__((address_space(3))) void*>(reinterpret_cast<uintptr_t>(l));
  __builtin_amdgcn_global_load_lds(gp, lp, 16, 0, 0);
}

// device-coherent 16B load: bypasses L1 (sc0) and L2 (sc1) -> reads at IC.
// Caller must s_waitcnt vmcnt(0) + sched_barrier(0) before consuming.
__device__ __forceinline__ u32x4 ld16c(const void* p) {
  u32x4 r;
  asm volatile("global_load_dwordx4 %0, %1, off sc0 sc1" : "=v"(r) : "v"(p));
  return r;
}

// ---------- prep: padded gathers + biases ----------
__global__ __launch_bounds__(256) void k_prep(const float* __restrict__ X,
                                              const float* __restrict__ Wih0,
                                              const float* __restrict__ bih0, const float* __restrict__ bhh0,
                                              const float* __restrict__ bih1, const float* __restrict__ bhh1,
                                              _Float16* __restrict__ Xt, _Float16* __restrict__ W0p,
                                              float* __restrict__ b0, float* __restrict__ b1) {
  const int S0 = TT * BB * KP, S1 = G4 * KP;
  int o = blockIdx.x * 256 + threadIdx.x;
  if (o < S0) {
    int k = o % KP, m = o / KP;
    int t = m >> 6, b = m & 63;
    Xt[o] = (_Float16)((k < INF) ? X[((size_t)b * TT + t) * INF + k] : 0.f);
    return;
  }
  o -= S0;
  if (o < S1) {
    int k = o % KP, n = o / KP;
    W0p[o] = (_Float16)((k < INF) ? Wih0[(size_t)n * INF + k] : 0.f);
    return;
  }
  o -= S1;
  if (o < G4) { b0[o] = bih0[o] + bhh0[o]; b1[o] = bih1[o] + bhh1[o]; }
}

// ---------- vectorized fp32->fp16 weight converts (8 elems/thread) ----------
__global__ __launch_bounds__(256) void k_cvt(const float* __restrict__ Whh0, const float* __restrict__ Wih1,
                                             const float* __restrict__ Whh1,
                                             _Float16* __restrict__ Whh0h, _Float16* __restrict__ Wih1h,
                                             _Float16* __restrict__ Whh1h) {
  const int N8 = G4 * HH / 8;
  int o = blockIdx.x * 256 + threadIdx.x;
  const float* src; _Float16* dst;
  if (o < N8)          { src = Whh0; dst = Whh0h; }
  else if (o < 2 * N8) { src = Wih1; dst = Wih1h; o -= N8; }
  else                 { src = Whh1; dst = Whh1h; o -= 2 * N8; }
  f4 a = *(const f4*)(src + (size_t)o * 8);
  f4 b = *(const f4*)(src + (size_t)o * 8 + 4);
  half8 h;
#pragma unroll
  for (int i = 0; i < 4; ++i) { h[i] = (_Float16)a[i]; h[4 + i] = (_Float16)b[i]; }
  *(half8*)(dst + (size_t)o * 8) = h;
}

// ---------- big GEMM (layer-0 input projection; writes swizzled xg0) ----------
__global__ __launch_bounds__(256) void k_gemm(const _Float16* __restrict__ A, const _Float16* __restrict__ Bw,
                                              const float* __restrict__ bias, _Float16* __restrict__ C,
                                              int K, int lda, int ldb) {
  __shared__ __align__(16) _Float16 As[4 * 128 * 8];
  __shared__ __align__(16) _Float16 Bs[4 * 128 * 8];
  const int tid = threadIdx.x;
  const int w = tid >> 6, lane = tid & 63;
  const int q = lane >> 4, ml = lane & 15;
  const int m0 = blockIdx.x * 128, n0 = blockIdx.y * 128;
  const int wm = (w >> 1) * 64, wn = (w & 1) * 64;
  f4 acc[4][4] = {};
  const int kt_iters = K >> 5;
  for (int kt = 0; kt < kt_iters; ++kt) {
    __syncthreads();
#pragma unroll
    for (int i = 0; i < 2; ++i) {
      int cb = i * 256 + w * 64;
      int kc = cb >> 7, mb = cb & 127;
      gld_lds16(A + (size_t)(m0 + mb + lane) * lda + kt * 32 + kc * 8, (char*)As + (size_t)cb * 16);
      gld_lds16(Bw + (size_t)(n0 + mb + lane) * ldb + kt * 32 + kc * 8, (char*)Bs + (size_t)cb * 16);
    }
    __syncthreads();
    half8 af[4], bf[4];
#pragma unroll
    for (int tm = 0; tm < 4; ++tm) af[tm] = *(const half8*)(As + ((size_t)q * 128 + wm + tm * 16 + ml) * 8);
#pragma unroll
    for (int tn = 0; tn < 4; ++tn) bf[tn] = *(const half8*)(Bs + ((size_t)q * 128 + wn + tn * 16 + ml) * 8);
#pragma unroll
    for (int tm = 0; tm < 4; ++tm)
#pragma unroll
      for (int tn = 0; tn < 4; ++tn)
        acc[tm][tn] = mfma16(af[tm], bf[tn], acc[tm][tn]);
  }
#pragma unroll
  for (int tn = 0; tn < 4; ++tn) {
    int n = n0 + wn + tn * 16 + ml;
    float bv = bias[n];
    int g_ = n >> 10, cl = n & 1023;
    size_t nsw = (size_t)(cl >> 4) * 4096 + (size_t)g_ * 512 + (cl & 15);
#pragma unroll
    for (int tm = 0; tm < 4; ++tm)
#pragma unroll
      for (int r = 0; r < 4; ++r) {
        int m = m0 + wm + tm * 16 + q * 4 + r;
        int t_ = m >> 6, b_ = m & 63;
        // swizzled xg0 offset (write granularity unchanged: 16 lanes x 2B runs)
        C[(size_t)t_ * 262144 + nsw + (size_t)(b_ >> 5) * 2048 + (b_ & 31) * 16]
            = (_Float16)(acc[tm][tn][r] + bv);
      }
  }
}

// ---------- layer-0 recurrence (data-as-flag; block-contiguous y & xg0) ----------
// y is 0xFF-initialized; each address written once; valid h finite => dword
// 0xFFFFFFFF is an unambiguous "not yet" sentinel.
__device__ __forceinline__ void rec_l0(const _Float16* __restrict__ xg, const _Float16* Whh,
                                       _Float16* y, int idx, int tid,
                                       float (*gl)[4][GLI]) {
  const int w = tid >> 6, lane = tid & 63;
  const int q = lane >> 4, ml = lane & 15;
  const int ug = idx & 63, mgp = idx >> 6;
  const int u0 = ug * 16, b0 = mgp * 32;
  const int brow = tid >> 4, u = tid & 15;
  const int bi = b0 + brow, col = u0 + u;
  (void)bi; (void)col;

  half8 bf[4][4];  // Whh slice: row = tn*HH+u0+ml, k = w*128 + kt*32 + q*8
#pragma unroll
  for (int tn = 0; tn < 4; ++tn)
#pragma unroll
    for (int kt = 0; kt < 4; ++kt)
      bf[tn][kt] = *(const half8*)(Whh + (size_t)(tn * HH + u0 + ml) * HH + w * 128 + kt * 32 + q * 8);

  // swizzled consumer base: rows b0+{tm*16+ml}, cols w*128+kt*32+q*8
  //   offset = t*65536 + (w*8 + kt*2 + (q>>1))*1024 + mgp*512 + (tm*16+ml)*16 + (q&1)*8
  const size_t hoff = (size_t)w * 8192 + ((q >> 1) * 1024 + (q & 1) * 8) + mgp * 512 + ml * 16;
  // swizzled producer address: my chunk, row brow, col pair (u,u+1)
  _Float16* ybase = y + (size_t)ug * 1024 + mgp * 512 + brow * 16 + u;
  // swizzled xg base: my block's contiguous 4KB chunk; thread offset = tid, gate stride 512
  const _Float16* xbase = xg + (size_t)ug * 4096 + (size_t)mgp * 2048 + tid;

  float c_reg = 0.f;

  for (int t = 0; t < TT; ++t) {
#pragma unroll
    for (int tn = 0; tn < 4; ++tn)
#pragma unroll
      for (int kt = 0; kt < 4; ++kt) asm volatile("" : "+v"(bf[tn][kt]));

    const _Float16* xp = xbase + (size_t)t * 262144;  // in flight during poll
    _Float16 xv0 = xp[0], xv1 = xp[512], xv2 = xp[1024], xv3 = xp[1536];
    f4 acc[4][2] = {};
    if (t > 0) {
      const _Float16* hp = y + (size_t)(t - 1) * 65536 + hoff;
      u32x4 rr[2][4];
      for (;;) {
#pragma unroll
        for (int tm = 0; tm < 2; ++tm)
#pragma unroll
          for (int kt = 0; kt < 4; ++kt)
            rr[tm][kt] = ld16c(hp + kt * 2048 + tm * 256);
        asm volatile("s_waitcnt vmcnt(0)" ::: "memory");
        __builtin_amdgcn_sched_barrier(0);
        unsigned mx = 0u;
#pragma unroll
        for (int tm = 0; tm < 2; ++tm)
#pragma unroll
          for (int kt = 0; kt < 4; ++kt)
#pragma unroll
            for (int j = 0; j < 4; ++j)
              mx = mx > rr[tm][kt][j] ? mx : rr[tm][kt][j];
        if (__all(mx != 0xFFFFFFFFu)) break;  // valid finite fp16 pairs < 0xFC00FC00
        __builtin_amdgcn_s_sleep(2);
      }
#pragma unroll
      for (int kt = 0; kt < 4; ++kt)
#pragma unroll
        for (int tm = 0; tm < 2; ++tm) {
          half8 av = __builtin_bit_cast(half8, rr[tm][kt]);
#pragma unroll
          for (int tn = 0; tn < 4; ++tn)
            acc[tn][tm] = mfma16(av, bf[tn][kt], acc[tn][tm]);
        }
    }
#pragma unroll
    for (int tn = 0; tn < 4; ++tn)
#pragma unroll
      for (int tm = 0; tm < 2; ++tm)
#pragma unroll
        for (int r = 0; r < 4; ++r)
          gl[w][tn][(tm * 16 + q * 4 + r) * GLS + ml] = acc[tn][tm][r];
    barrier_lds();

    float g0 = (float)xv0, g1 = (float)xv1, g2 = (float)xv2, g3 = (float)xv3;
#pragma unroll
    for (int kw = 0; kw < 8; ++kw) {
      g0 += gl[kw][0][brow * GLS + u]; g1 += gl[kw][1][brow * GLS + u];
      g2 += gl[kw][2][brow * GLS + u]; g3 += gl[kw][3][brow * GLS + u];
    }
    float I = 1.f / (1.f + __expf(-g0));
    float F = 1.f / (1.f + __expf(-g1));
    float G = ftanh(g2);
    float O = 1.f / (1.f + __expf(-g3));
    c_reg = F * c_reg + I * G;
    unsigned hv = (unsigned)__builtin_bit_cast(unsigned short, (_Float16)(O * ftanh(c_reg)));
    unsigned other = (unsigned)__shfl_xor((int)hv, 1);
    if ((tid & 1) == 0) {
      // fire-and-forget; full-line single-owner writes (wave covers one 128B line)
      unsigned word = hv | (other << 16);
      __hip_atomic_store((unsigned*)(ybase + (size_t)t * 65536), word,
                         __ATOMIC_RELAXED, __HIP_MEMORY_SCOPE_AGENT);
    }
    barrier_lds();
  }
}

// ---------- layer-1 recurrence: gates = [Wih1|Whh1] @ [y1[t]; y2[t-1]] + b1 ----------
__device__ __forceinline__ void rec_l1(const _Float16* Wih1, const _Float16* Whh1,
                                       const float* __restrict__ b1,
                                       const _Float16* __restrict__ y1, _Float16* y2,
                                       int idx, int tid, float (*gl)[4][GLI]) {
  const int w = tid >> 6, lane = tid & 63;
  const int q = lane >> 4, ml = lane & 15;
  const int ug = idx & 63, mgp = idx >> 6;
  const int u0 = ug * 16, b0 = mgp * 32;
  const int brow = tid >> 4, u = tid & 15;
  const int col = u0 + u;
  const int ws = w & 3;  // k-slice [ws*256..+256) within Wih1 (w<4) or Whh1 (w>=4)

  const _Float16* Bmat = (w < 4) ? Wih1 : Whh1;
  half8 bf[4][8];
#pragma unroll
  for (int tn = 0; tn < 4; ++tn)
#pragma unroll
    for (int kt = 0; kt < 8; ++kt)
      bf[tn][kt] = *(const half8*)(Bmat + (size_t)(tn * HH + u0 + ml) * HH + ws * 256 + kt * 32 + q * 8);

  const float bv0 = b1[col], bv1 = b1[HH + col], bv2 = b1[2 * HH + col], bv3 = b1[3 * HH + col];
  // swizzled consumer base: cols ws*256+kt*32+q*8 -> ug' = ws*16 + kt*2 + (q>>1)
  const size_t hoff = (size_t)ws * 16384 + ((q >> 1) * 1024 + (q & 1) * 8) + mgp * 512 + ml * 16;
  _Float16* ybase = y2 + (size_t)ug * 1024 + mgp * 512 + brow * 16 + u;
  float c_reg = 0.f;

  for (int t = 0; t < TT; ++t) {
#pragma unroll
    for (int tn = 0; tn < 4; ++tn)
#pragma unroll
      for (int kt = 0; kt < 8; ++kt) asm volatile("" : "+v"(bf[tn][kt]));

    f4 acc[4][2] = {};
    const bool active = (w < 4) || (t > 0);
    if (active) {
      const _Float16* hp = ((w < 4) ? (y1 + (size_t)t * 65536)
                                    : (y2 + (size_t)(t - 1) * 65536)) + hoff;
      u32x4 rr[2][8];
      for (;;) {
#pragma unroll
        for (int tm = 0; tm < 2; ++tm)
#pragma unroll
          for (int kt = 0; kt < 8; ++kt)
            rr[tm][kt] = ld16c(hp + kt * 2048 + tm * 256);
        asm volatile("s_waitcnt vmcnt(0)" ::: "memory");
        __builtin_amdgcn_sched_barrier(0);
        unsigned mx = 0u;
#pragma unroll
        for (int tm = 0; tm < 2; ++tm)
#pragma unroll
          for (int kt = 0; kt < 8; ++kt)
#pragma unroll
            for (int j = 0; j < 4; ++j)
              mx = mx > rr[tm][kt][j] ? mx : rr[tm][kt][j];
        if (__all(mx != 0xFFFFFFFFu)) break;
        __builtin_amdgcn_s_sleep(2);
      }
#pragma unroll
      for (int kt = 0; kt < 8; ++kt)
#pragma unroll
        for (int tm = 0; tm < 2; ++tm) {
          half8 av = __builtin_bit_cast(half8, rr[tm][kt]);
#pragma unroll
          for (int tn = 0; tn < 4; ++tn)
            acc[tn][tm] = mfma16(av, bf[tn][kt], acc[tn][tm]);
        }
    }
#pragma unroll
    for (int tn = 0; tn < 4; ++tn)
#pragma unroll
      for (int tm = 0; tm < 2; ++tm)
#pragma unroll
        for (int r = 0; r < 4; ++r)
          gl[w][tn][(tm * 16 + q * 4 + r) * GLS + ml] = acc[tn][tm][r];
    barrier_lds();

    float g0 = bv0, g1 = bv1, g2 = bv2, g3 = bv3;
#pragma unroll
    for (int kw = 0; kw < 8; ++kw) {
      g0 += gl[kw][0][brow * GLS + u]; g1 += gl[kw][1][brow * GLS + u];
      g2 += gl[kw][2][brow * GLS + u]; g3 += gl[kw][3][brow * GLS + u];
    }
    float I = 1.f / (1.f + __expf(-g0));
    float F = 1.f / (1.f + __expf(-g1));
    float G = ftanh(g2);
    float O = 1.f / (1.f + __expf(-g3));
    c_reg = F * c_reg + I * G;
    unsigned hv = (unsigned)__builtin_bit_cast(unsigned short, (_Float16)(O * ftanh(c_reg)));
    unsigned other = (unsigned)__shfl_xor((int)hv, 1);
    if ((tid & 1) == 0) {
      unsigned word = hv | (other << 16);
      __hip_atomic_store((unsigned*)(ybase + (size_t)t * 65536), word,
                         __ATOMIC_RELAXED, __HIP_MEMORY_SCOPE_AGENT);
    }
    barrier_lds();
  }
}

// ---------- fused both-layer recurrence: 256 blocks = 1/CU ----------
__global__ __launch_bounds__(512, 1) void k_rec2(const _Float16* __restrict__ xg0,
                                                 const _Float16* Whh0, const _Float16* Wih1,
                                                 const _Float16* Whh1, const float* __restrict__ b1,
                                                 _Float16* y1, _Float16* y2) {
  __shared__ __align__(16) float gl[8][4][GLI];  // 88 KB: >80KB guarantees 1 block/CU
  const int bid = blockIdx.x, tid = threadIdx.x;
  if (bid < 128)
    rec_l0(xg0, Whh0, y1, bid, tid, gl);
  else
    rec_l1(Wih1, Whh1, b1, y1, y2, bid - 128, tid, gl);
}

// ---------- output head (reads swizzled y2) ----------
__global__ __launch_bounds__(256) void k_out(const _Float16* __restrict__ y2, const float* __restrict__ Wy,
                                             const float* __restrict__ by, float* __restrict__ out) {
  int gw = blockIdx.x * 4 + (threadIdx.x >> 6);
  int lane = threadIdx.x & 63;
  int t = gw >> 6, b = gw & 63;
  // element (t,b,k): offset = t*65536 + (k>>4)*1024 + (b>>5)*512 + (b&31)*16 + (k&15)
  const _Float16* base = y2 + (size_t)t * 65536 + (size_t)(lane >> 4) * 1024
                            + (size_t)(b >> 5) * 512 + (size_t)(b & 31) * 16 + (lane & 15);
  float p0 = 0.f, p1 = 0.f;
#pragma unroll
  for (int i = 0; i < 16; ++i) {
    int k = i * 64 + lane;
    float v = tanhf((float)base[(size_t)i * 4096]);
    p0 += v * Wy[k];
    p1 += v * Wy[HH + k];
  }
  for (int off = 32; off > 0; off >>= 1) {
    p0 += __shfl_down(p0, off);
    p1 += __shfl_down(p1, off);
  }
  if (lane == 0) {
    out[((size_t)b * TT + t) * 2 + 0] = p0 + by[0];
    out[((size_t)b * TT + t) * 2 + 1] = p1 + by[1];
  }
}

extern "C" void kernel_launch(void* const* d_in, const int* in_sizes, int n_in,
                              void* d_out, int out_size, void* d_ws, size_t ws_size,
                              hipStream_t stream) {
  (void)in_sizes; (void)n_in; (void)out_size; (void)ws_size;
  const float* X    = (const float*)d_in[0];
  const float* Wih0 = (const float*)d_in[3];
  const float* Whh0 = (const float*)d_in[4];
  const float* bih0 = (const float*)d_in[5];
  const float* bhh0 = (const float*)d_in[6];
  const float* Wih1 = (const float*)d_in[7];
  const float* Whh1 = (const float*)d_in[8];
  const float* bih1 = (const float*)d_in[9];
  const float* bhh1 = (const float*)d_in[10];
  const float* Wy   = (const float*)d_in[11];
  const float* by   = (const float*)d_in[12];
  float* out = (float*)d_out;

  char* p = (char*)d_ws;
  auto carve = [&](size_t bytes) { char* r = p; p += (bytes + 255) & ~(size_t)255; return r; };
  _Float16* Xt    = (_Float16*)carve((size_t)TT * BB * KP * 2);
  _Float16* W0p   = (_Float16*)carve((size_t)G4 * KP * 2);
  _Float16* Whh0h = (_Float16*)carve((size_t)G4 * HH * 2);
  _Float16* Wih1h = (_Float16*)carve((size_t)G4 * HH * 2);
  _Float16* Whh1h = (_Float16*)carve((size_t)G4 * HH * 2);
  float* b0 = (float*)carve((size_t)G4 * 4);
  float* b1 = (float*)carve((size_t)G4 * 4);
  _Float16* xg0 = (_Float16*)carve((size_t)TT * BB * G4 * 2);
  _Float16* y1  = (_Float16*)carve((size_t)TT * BB * HH * 2);
  _Float16* y2  = (_Float16*)carve((size_t)TT * BB * HH * 2);

  // sentinel init: 0xFF bytes => every fp16 pair reads 0xFFFFFFFF (NaN,NaN),
  // which valid h (always finite, |h|<=1) can never produce.
  hipMemsetAsync(y1, 0xFF, (size_t)TT * BB * HH * 2, stream);
  hipMemsetAsync(y2, 0xFF, (size_t)TT * BB * HH * 2, stream);

  const int prep_total = TT * BB * KP + G4 * KP + G4;
  k_prep<<<(prep_total + 255) / 256, 256, 0, stream>>>(X, Wih0, bih0, bhh0, bih1, bhh1,
                                                       Xt, W0p, b0, b1);
  k_cvt<<<3 * (G4 * HH / 8) / 256, 256, 0, stream>>>(Whh0, Wih1, Whh1, Whh0h, Wih1h, Whh1h);
  k_gemm<<<dim3(TT * BB / 128, G4 / 128), 256, 0, stream>>>(Xt, W0p, b0, xg0, KP, KP, KP);
  k_rec2<<<256, 512, 0, stream>>>(xg0, Whh0h, Wih1h, Whh1h, b1, y1, y2);
  k_out<<<(TT * BB) / 4, 256, 0, stream>>>(y2, Wy, by, out);
}

// Round 12
// 571.839 us; speedup vs baseline: 1.0084x; 1.0084x over previous
//
#include <hip/hip_runtime.h>
#include <stdint.h>

#define BB 64
#define TT 128
#define INF 257
#define KP 288
#define HH 1024
#define G4 4096
#define GLS 20            // gl row stride (floats)
#define GLI (32 * GLS + 64)  // padded inner extent -> 88KB LDS, forces 1 block/CU

// swizzled y layout: [t][ug(64)][mgp(2)][r(32)][c(16)] fp16
//   element (t, row, col): ug=col>>4, c=col&15, mgp=row>>5, r=row&31
//   offset = t*65536 + ug*1024 + mgp*512 + r*16 + c
// swizzled xg0 layout: [t][ug(64)][mgp(2)][g(4)][r(32)][c(16)] fp16
//   element (t, b, n=g*1024+col): offset = t*262144 + ug*4096 + mgp*2048
//                                          + g*512 + r*16 + c

typedef _Float16 half8 __attribute__((ext_vector_type(8)));
typedef float f4 __attribute__((ext_vector_type(4)));
typedef unsigned u32x4 __attribute__((ext_vector_type(4)));

__device__ __forceinline__ f4 mfma16(half8 a, half8 b, f4 c) {
  return __builtin_amdgcn_mfma_f32_16x16x32_f16(a, b, c, 0, 0, 0);
}

// LDS-only barrier: orders ds ops but does NOT drain vmcnt (h-stores stay async)
__device__ __forceinline__ void barrier_lds() {
  asm volatile("s_waitcnt lgkmcnt(0)\n\ts_barrier" ::: "memory");
}

// fast tanh via v_exp: tanh(x) = 1 - 2/(1+e^{2x}); saturates to +-1, no NaN path
__device__ __forceinline__ float ftanh(float x) {
  return 1.f - 2.f / (1.f + __expf(2.f * x));
}

// async global->LDS, 16B per lane
__device__ __forceinline__ void gld_lds16(const void* g, void* l) {
  auto gp = reinterpret_cast<__attribute__((address_space(1))) void*>(reinterpret_cast<uintptr_t>(g));
  auto lp = reinterpret_cast<__attribute__((address_space(3))) void*>(reinterpret_cast<uintptr_t>(l));
  __builtin_amdgcn_global_load_lds(gp, lp, 16, 0, 0);
}

// device-coherent 16B load: bypasses L1 (sc0) and L2 (sc1) -> reads at IC.
// Caller must s_waitcnt vmcnt(0) + sched_barrier(0) before consuming.
__device__ __forceinline__ u32x4 ld16c(const void* p) {
  u32x4 r;
  asm volatile("global_load_dwordx4 %0, %1, off sc0 sc1" : "=v"(r) : "v"(p));
  return r;
}

// write-through 16B store: bypasses L1/L2 -> lands at the memory-side
// coherence point (IC). Used to pre-warm the sentinel-filled y arrays into
// the IC so per-step producer stores merge into RESIDENT lines instead of
// paying a ~900cy HBM line-fetch on the visibility path.
__device__ __forceinline__ void st16c(void* p, u32x4 v) {
  asm volatile("global_store_dwordx4 %0, %1, off sc0 sc1" :: "v"(p), "v"(v) : "memory");
}

// ---------- sentinel init: y lines land (and stay) at the IC ----------
__global__ __launch_bounds__(256) void k_init(_Float16* __restrict__ y1, _Float16* __restrict__ y2) {
  const u32x4 s = {0xFFFFFFFFu, 0xFFFFFFFFu, 0xFFFFFFFFu, 0xFFFFFFFFu};
  const size_t n16 = (size_t)TT * BB * HH * 2 / 16;  // 16B chunks per array
  size_t i = (size_t)blockIdx.x * 256 + threadIdx.x;
  const size_t stride = (size_t)gridDim.x * 256;
  for (; i < n16; i += stride) {
    st16c((char*)y1 + i * 16, s);
    st16c((char*)y2 + i * 16, s);
  }
}

// ---------- prep: padded gathers + biases ----------
__global__ __launch_bounds__(256) void k_prep(const float* __restrict__ X,
                                              const float* __restrict__ Wih0,
                                              const float* __restrict__ bih0, const float* __restrict__ bhh0,
                                              const float* __restrict__ bih1, const float* __restrict__ bhh1,
                                              _Float16* __restrict__ Xt, _Float16* __restrict__ W0p,
                                              float* __restrict__ b0, float* __restrict__ b1) {
  const int S0 = TT * BB * KP, S1 = G4 * KP;
  int o = blockIdx.x * 256 + threadIdx.x;
  if (o < S0) {
    int k = o % KP, m = o / KP;
    int t = m >> 6, b = m & 63;
    Xt[o] = (_Float16)((k < INF) ? X[((size_t)b * TT + t) * INF + k] : 0.f);
    return;
  }
  o -= S0;
  if (o < S1) {
    int k = o % KP, n = o / KP;
    W0p[o] = (_Float16)((k < INF) ? Wih0[(size_t)n * INF + k] : 0.f);
    return;
  }
  o -= S1;
  if (o < G4) { b0[o] = bih0[o] + bhh0[o]; b1[o] = bih1[o] + bhh1[o]; }
}

// ---------- vectorized fp32->fp16 weight converts (8 elems/thread) ----------
__global__ __launch_bounds__(256) void k_cvt(const float* __restrict__ Whh0, const float* __restrict__ Wih1,
                                             const float* __restrict__ Whh1,
                                             _Float16* __restrict__ Whh0h, _Float16* __restrict__ Wih1h,
                                             _Float16* __restrict__ Whh1h) {
  const int N8 = G4 * HH / 8;
  int o = blockIdx.x * 256 + threadIdx.x;
  const float* src; _Float16* dst;
  if (o < N8)          { src = Whh0; dst = Whh0h; }
  else if (o < 2 * N8) { src = Wih1; dst = Wih1h; o -= N8; }
  else                 { src = Whh1; dst = Whh1h; o -= 2 * N8; }
  f4 a = *(const f4*)(src + (size_t)o * 8);
  f4 b = *(const f4*)(src + (size_t)o * 8 + 4);
  half8 h;
#pragma unroll
  for (int i = 0; i < 4; ++i) { h[i] = (_Float16)a[i]; h[4 + i] = (_Float16)b[i]; }
  *(half8*)(dst + (size_t)o * 8) = h;
}

// ---------- big GEMM (layer-0 input projection; writes swizzled xg0) ----------
__global__ __launch_bounds__(256) void k_gemm(const _Float16* __restrict__ A, const _Float16* __restrict__ Bw,
                                              const float* __restrict__ bias, _Float16* __restrict__ C,
                                              int K, int lda, int ldb) {
  __shared__ __align__(16) _Float16 As[4 * 128 * 8];
  __shared__ __align__(16) _Float16 Bs[4 * 128 * 8];
  const int tid = threadIdx.x;
  const int w = tid >> 6, lane = tid & 63;
  const int q = lane >> 4, ml = lane & 15;
  const int m0 = blockIdx.x * 128, n0 = blockIdx.y * 128;
  const int wm = (w >> 1) * 64, wn = (w & 1) * 64;
  f4 acc[4][4] = {};
  const int kt_iters = K >> 5;
  for (int kt = 0; kt < kt_iters; ++kt) {
    __syncthreads();
#pragma unroll
    for (int i = 0; i < 2; ++i) {
      int cb = i * 256 + w * 64;
      int kc = cb >> 7, mb = cb & 127;
      gld_lds16(A + (size_t)(m0 + mb + lane) * lda + kt * 32 + kc * 8, (char*)As + (size_t)cb * 16);
      gld_lds16(Bw + (size_t)(n0 + mb + lane) * ldb + kt * 32 + kc * 8, (char*)Bs + (size_t)cb * 16);
    }
    __syncthreads();
    half8 af[4], bf[4];
#pragma unroll
    for (int tm = 0; tm < 4; ++tm) af[tm] = *(const half8*)(As + ((size_t)q * 128 + wm + tm * 16 + ml) * 8);
#pragma unroll
    for (int tn = 0; tn < 4; ++tn) bf[tn] = *(const half8*)(Bs + ((size_t)q * 128 + wn + tn * 16 + ml) * 8);
#pragma unroll
    for (int tm = 0; tm < 4; ++tm)
#pragma unroll
      for (int tn = 0; tn < 4; ++tn)
        acc[tm][tn] = mfma16(af[tm], bf[tn], acc[tm][tn]);
  }
#pragma unroll
  for (int tn = 0; tn < 4; ++tn) {
    int n = n0 + wn + tn * 16 + ml;
    float bv = bias[n];
    int g_ = n >> 10, cl = n & 1023;
    size_t nsw = (size_t)(cl >> 4) * 4096 + (size_t)g_ * 512 + (cl & 15);
#pragma unroll
    for (int tm = 0; tm < 4; ++tm)
#pragma unroll
      for (int r = 0; r < 4; ++r) {
        int m = m0 + wm + tm * 16 + q * 4 + r;
        int t_ = m >> 6, b_ = m & 63;
        C[(size_t)t_ * 262144 + nsw + (size_t)(b_ >> 5) * 2048 + (b_ & 31) * 16]
            = (_Float16)(acc[tm][tn][r] + bv);
      }
  }
}

// ---------- layer-0 recurrence (data-as-flag; block-contiguous y & xg0) ----------
__device__ __forceinline__ void rec_l0(const _Float16* __restrict__ xg, const _Float16* Whh,
                                       _Float16* y, int idx, int tid,
                                       float (*gl)[4][GLI]) {
  const int w = tid >> 6, lane = tid & 63;
  const int q = lane >> 4, ml = lane & 15;
  const int ug = idx & 63, mgp = idx >> 6;
  const int u0 = ug * 16;
  const int brow = tid >> 4, u = tid & 15;

  half8 bf[4][4];  // Whh slice: row = tn*HH+u0+ml, k = w*128 + kt*32 + q*8
#pragma unroll
  for (int tn = 0; tn < 4; ++tn)
#pragma unroll
    for (int kt = 0; kt < 4; ++kt)
      bf[tn][kt] = *(const half8*)(Whh + (size_t)(tn * HH + u0 + ml) * HH + w * 128 + kt * 32 + q * 8);

  const size_t hoff = (size_t)w * 8192 + ((q >> 1) * 1024 + (q & 1) * 8) + mgp * 512 + ml * 16;
  _Float16* ybase = y + (size_t)ug * 1024 + mgp * 512 + brow * 16 + u;
  const _Float16* xbase = xg + (size_t)ug * 4096 + (size_t)mgp * 2048 + tid;

  float c_reg = 0.f;

  for (int t = 0; t < TT; ++t) {
#pragma unroll
    for (int tn = 0; tn < 4; ++tn)
#pragma unroll
      for (int kt = 0; kt < 4; ++kt) asm volatile("" : "+v"(bf[tn][kt]));

    const _Float16* xp = xbase + (size_t)t * 262144;  // in flight during poll
    _Float16 xv0 = xp[0], xv1 = xp[512], xv2 = xp[1024], xv3 = xp[1536];
    f4 acc[4][2] = {};
    if (t > 0) {
      const _Float16* hp = y + (size_t)(t - 1) * 65536 + hoff;
      u32x4 rr[2][4];
      for (;;) {
#pragma unroll
        for (int tm = 0; tm < 2; ++tm)
#pragma unroll
          for (int kt = 0; kt < 4; ++kt)
            rr[tm][kt] = ld16c(hp + kt * 2048 + tm * 256);
        asm volatile("s_waitcnt vmcnt(0)" ::: "memory");
        __builtin_amdgcn_sched_barrier(0);
        unsigned mx = 0u;
#pragma unroll
        for (int tm = 0; tm < 2; ++tm)
#pragma unroll
          for (int kt = 0; kt < 4; ++kt)
#pragma unroll
            for (int j = 0; j < 4; ++j)
              mx = mx > rr[tm][kt][j] ? mx : rr[tm][kt][j];
        if (__all(mx != 0xFFFFFFFFu)) break;  // valid finite fp16 pairs < 0xFC00FC00
        __builtin_amdgcn_s_sleep(2);
      }
#pragma unroll
      for (int kt = 0; kt < 4; ++kt)
#pragma unroll
        for (int tm = 0; tm < 2; ++tm) {
          half8 av = __builtin_bit_cast(half8, rr[tm][kt]);
#pragma unroll
          for (int tn = 0; tn < 4; ++tn)
            acc[tn][tm] = mfma16(av, bf[tn][kt], acc[tn][tm]);
        }
    }
#pragma unroll
    for (int tn = 0; tn < 4; ++tn)
#pragma unroll
      for (int tm = 0; tm < 2; ++tm)
#pragma unroll
        for (int r = 0; r < 4; ++r)
          gl[w][tn][(tm * 16 + q * 4 + r) * GLS + ml] = acc[tn][tm][r];
    barrier_lds();

    float g0 = (float)xv0, g1 = (float)xv1, g2 = (float)xv2, g3 = (float)xv3;
#pragma unroll
    for (int kw = 0; kw < 8; ++kw) {
      g0 += gl[kw][0][brow * GLS + u]; g1 += gl[kw][1][brow * GLS + u];
      g2 += gl[kw][2][brow * GLS + u]; g3 += gl[kw][3][brow * GLS + u];
    }
    float I = 1.f / (1.f + __expf(-g0));
    float F = 1.f / (1.f + __expf(-g1));
    float G = ftanh(g2);
    float O = 1.f / (1.f + __expf(-g3));
    c_reg = F * c_reg + I * G;
    unsigned hv = (unsigned)__builtin_bit_cast(unsigned short, (_Float16)(O * ftanh(c_reg)));
    unsigned other = (unsigned)__shfl_xor((int)hv, 1);
    if ((tid & 1) == 0) {
      unsigned word = hv | (other << 16);
      __hip_atomic_store((unsigned*)(ybase + (size_t)t * 65536), word,
                         __ATOMIC_RELAXED, __HIP_MEMORY_SCOPE_AGENT);
    }
    barrier_lds();
  }
}

// ---------- layer-1 recurrence: gates = [Wih1|Whh1] @ [y1[t]; y2[t-1]] + b1 ----------
__device__ __forceinline__ void rec_l1(const _Float16* Wih1, const _Float16* Whh1,
                                       const float* __restrict__ b1,
                                       const _Float16* __restrict__ y1, _Float16* y2,
                                       int idx, int tid, float (*gl)[4][GLI]) {
  const int w = tid >> 6, lane = tid & 63;
  const int q = lane >> 4, ml = lane & 15;
  const int ug = idx & 63, mgp = idx >> 6;
  const int u0 = ug * 16;
  const int brow = tid >> 4, u = tid & 15;
  const int col = u0 + u;
  const int ws = w & 3;  // k-slice [ws*256..+256) within Wih1 (w<4) or Whh1 (w>=4)

  const _Float16* Bmat = (w < 4) ? Wih1 : Whh1;
  half8 bf[4][8];
#pragma unroll
  for (int tn = 0; tn < 4; ++tn)
#pragma unroll
    for (int kt = 0; kt < 8; ++kt)
      bf[tn][kt] = *(const half8*)(Bmat + (size_t)(tn * HH + u0 + ml) * HH + ws * 256 + kt * 32 + q * 8);

  const float bv0 = b1[col], bv1 = b1[HH + col], bv2 = b1[2 * HH + col], bv3 = b1[3 * HH + col];
  const size_t hoff = (size_t)ws * 16384 + ((q >> 1) * 1024 + (q & 1) * 8) + mgp * 512 + ml * 16;
  _Float16* ybase = y2 + (size_t)ug * 1024 + mgp * 512 + brow * 16 + u;
  float c_reg = 0.f;

  for (int t = 0; t < TT; ++t) {
#pragma unroll
    for (int tn = 0; tn < 4; ++tn)
#pragma unroll
      for (int kt = 0; kt < 8; ++kt) asm volatile("" : "+v"(bf[tn][kt]));

    f4 acc[4][2] = {};
    const bool active = (w < 4) || (t > 0);
    if (active) {
      const _Float16* hp = ((w < 4) ? (y1 + (size_t)t * 65536)
                                    : (y2 + (size_t)(t - 1) * 65536)) + hoff;
      u32x4 rr[2][8];
      for (;;) {
#pragma unroll
        for (int tm = 0; tm < 2; ++tm)
#pragma unroll
          for (int kt = 0; kt < 8; ++kt)
            rr[tm][kt] = ld16c(hp + kt * 2048 + tm * 256);
        asm volatile("s_waitcnt vmcnt(0)" ::: "memory");
        __builtin_amdgcn_sched_barrier(0);
        unsigned mx = 0u;
#pragma unroll
        for (int tm = 0; tm < 2; ++tm)
#pragma unroll
          for (int kt = 0; kt < 8; ++kt)
#pragma unroll
            for (int j = 0; j < 4; ++j)
              mx = mx > rr[tm][kt][j] ? mx : rr[tm][kt][j];
        if (__all(mx != 0xFFFFFFFFu)) break;
        __builtin_amdgcn_s_sleep(2);
      }
#pragma unroll
      for (int kt = 0; kt < 8; ++kt)
#pragma unroll
        for (int tm = 0; tm < 2; ++tm) {
          half8 av = __builtin_bit_cast(half8, rr[tm][kt]);
#pragma unroll
          for (int tn = 0; tn < 4; ++tn)
            acc[tn][tm] = mfma16(av, bf[tn][kt], acc[tn][tm]);
        }
    }
#pragma unroll
    for (int tn = 0; tn < 4; ++tn)
#pragma unroll
      for (int tm = 0; tm < 2; ++tm)
#pragma unroll
        for (int r = 0; r < 4; ++r)
          gl[w][tn][(tm * 16 + q * 4 + r) * GLS + ml] = acc[tn][tm][r];
    barrier_lds();

    float g0 = bv0, g1 = bv1, g2 = bv2, g3 = bv3;
#pragma unroll
    for (int kw = 0; kw < 8; ++kw) {
      g0 += gl[kw][0][brow * GLS + u]; g1 += gl[kw][1][brow * GLS + u];
      g2 += gl[kw][2][brow * GLS + u]; g3 += gl[kw][3][brow * GLS + u];
    }
    float I = 1.f / (1.f + __expf(-g0));
    float F = 1.f / (1.f + __expf(-g1));
    float G = ftanh(g2);
    float O = 1.f / (1.f + __expf(-g3));
    c_reg = F * c_reg + I * G;
    unsigned hv = (unsigned)__builtin_bit_cast(unsigned short, (_Float16)(O * ftanh(c_reg)));
    unsigned other = (unsigned)__shfl_xor((int)hv, 1);
    if ((tid & 1) == 0) {
      unsigned word = hv | (other << 16);
      __hip_atomic_store((unsigned*)(ybase + (size_t)t * 65536), word,
                         __ATOMIC_RELAXED, __HIP_MEMORY_SCOPE_AGENT);
    }
    barrier_lds();
  }
}

// ---------- fused both-layer recurrence: 256 blocks = 1/CU ----------
__global__ __launch_bounds__(512, 1) void k_rec2(const _Float16* __restrict__ xg0,
                                                 const _Float16* Whh0, const _Float16* Wih1,
                                                 const _Float16* Whh1, const float* __restrict__ b1,
                                                 _Float16* y1, _Float16* y2) {
  __shared__ __align__(16) float gl[8][4][GLI];  // 88 KB: >80KB guarantees 1 block/CU
  const int bid = blockIdx.x, tid = threadIdx.x;
  if (bid < 128)
    rec_l0(xg0, Whh0, y1, bid, tid, gl);
  else
    rec_l1(Wih1, Whh1, b1, y1, y2, bid - 128, tid, gl);
}

// ---------- output head (reads swizzled y2) ----------
__global__ __launch_bounds__(256) void k_out(const _Float16* __restrict__ y2, const float* __restrict__ Wy,
                                             const float* __restrict__ by, float* __restrict__ out) {
  int gw = blockIdx.x * 4 + (threadIdx.x >> 6);
  int lane = threadIdx.x & 63;
  int t = gw >> 6, b = gw & 63;
  // element (t,b,k): offset = t*65536 + (k>>4)*1024 + (b>>5)*512 + (b&31)*16 + (k&15)
  const _Float16* base = y2 + (size_t)t * 65536 + (size_t)(lane >> 4) * 1024
                            + (size_t)(b >> 5) * 512 + (size_t)(b & 31) * 16 + (lane & 15);
  float p0 = 0.f, p1 = 0.f;
#pragma unroll
  for (int i = 0; i < 16; ++i) {
    int k = i * 64 + lane;
    float v = tanhf((float)base[(size_t)i * 4096]);
    p0 += v * Wy[k];
    p1 += v * Wy[HH + k];
  }
  for (int off = 32; off > 0; off >>= 1) {
    p0 += __shfl_down(p0, off);
    p1 += __shfl_down(p1, off);
  }
  if (lane == 0) {
    out[((size_t)b * TT + t) * 2 + 0] = p0 + by[0];
    out[((size_t)b * TT + t) * 2 + 1] = p1 + by[1];
  }
}

extern "C" void kernel_launch(void* const* d_in, const int* in_sizes, int n_in,
                              void* d_out, int out_size, void* d_ws, size_t ws_size,
                              hipStream_t stream) {
  (void)in_sizes; (void)n_in; (void)out_size; (void)ws_size;
  const float* X    = (const float*)d_in[0];
  const float* Wih0 = (const float*)d_in[3];
  const float* Whh0 = (const float*)d_in[4];
  const float* bih0 = (const float*)d_in[5];
  const float* bhh0 = (const float*)d_in[6];
  const float* Wih1 = (const float*)d_in[7];
  const float* Whh1 = (const float*)d_in[8];
  const float* bih1 = (const float*)d_in[9];
  const float* bhh1 = (const float*)d_in[10];
  const float* Wy   = (const float*)d_in[11];
  const float* by   = (const float*)d_in[12];
  float* out = (float*)d_out;

  char* p = (char*)d_ws;
  auto carve = [&](size_t bytes) { char* r = p; p += (bytes + 255) & ~(size_t)255; return r; };
  _Float16* Xt    = (_Float16*)carve((size_t)TT * BB * KP * 2);
  _Float16* W0p   = (_Float16*)carve((size_t)G4 * KP * 2);
  _Float16* Whh0h = (_Float16*)carve((size_t)G4 * HH * 2);
  _Float16* Wih1h = (_Float16*)carve((size_t)G4 * HH * 2);
  _Float16* Whh1h = (_Float16*)carve((size_t)G4 * HH * 2);
  float* b0 = (float*)carve((size_t)G4 * 4);
  float* b1 = (float*)carve((size_t)G4 * 4);
  _Float16* xg0 = (_Float16*)carve((size_t)TT * BB * G4 * 2);
  _Float16* y1  = (_Float16*)carve((size_t)TT * BB * HH * 2);
  _Float16* y2  = (_Float16*)carve((size_t)TT * BB * HH * 2);

  // sentinel init via write-through stores: lines end IC-resident (not just
  // HBM-backed), so every per-step producer store merges at the coherence
  // point without a ~900cy HBM line-fetch on the visibility path.
  k_init<<<2048, 256, 0, stream>>>(y1, y2);

  const int prep_total = TT * BB * KP + G4 * KP + G4;
  k_prep<<<(prep_total + 255) / 256, 256, 0, stream>>>(X, Wih0, bih0, bhh0, bih1, bhh1,
                                                       Xt, W0p, b0, b1);
  k_cvt<<<3 * (G4 * HH / 8) / 256, 256, 0, stream>>>(Whh0, Wih1, Whh1, Whh0h, Wih1h, Whh1h);
  k_gemm<<<dim3(TT * BB / 128, G4 / 128), 256, 0, stream>>>(Xt, W0p, b0, xg0, KP, KP, KP);
  k_rec2<<<256, 512, 0, stream>>>(xg0, Whh0h, Wih1h, Whh1h, b1, y1, y2);
  k_out<<<(TT * BB) / 4, 256, 0, stream>>>(y2, Wy, by, out);
}